// Round 2
// baseline (73.557 us; speedup 1.0000x reference)
//
#include <hip/hip_runtime.h>

#define N 1024
#define M 2048
#define P 20
#define THREADS 256            // 4 waves/block
#define WAVES 4
#define PPB 2                  // pred rows per block
#define BLOCKS (N / PPB)       // 512 blocks
#define RPT (M / THREADS)      // 8 gt rows per thread
#define HALF (RPT / 2)         // 4 rows per stream

typedef unsigned long long u64;

// out layout (float*): matched_points [0,40960) row n at n*40
//                      confidence     [40960,41984) at 40960+n
//                      indices(float) [41984,43008) at 41984+n
//
// R14: same single-kernel no-ws/no-atomic structure as R13 (verified absmax
// 0.0, dur 65.3). Changes are latency-hiding only:
//   1. Full unroll of the gt row loop (8 independent float4 load batches
//      issued early -> deeper MLP over ~200cy L2-hit latency).
//   2. Two independent min-streams: rows {0..3}*256+tid (all m < 1024+tid)
//      and rows {4..7}*256+tid (all m >= 1024+tid). Every stream-A index is
//      strictly less than every stream-B index, so the final packed-u64 min
//      (dist_bits<<32 | idx) preserves first-occurrence argmin exactly.
// Numerics: inner-loop expression, accumulation order, acc*(1/P), packed-key
// semantics, expf epilogue all expression-identical to R9-R13.
//
// Decomposition evidence (R13 rocprof): top-5 dispatches are all harness
// 256MiB ws-poison fills at ~40us / 84% HBM peak (memory roofline,
// harness-owned). Kernel floor: 167MB L2 re-read ~4.9us + 210M VALU ops
// ~2.7us + 42M v_sqrt ~2.1us, overlapped ~5-6us. This round targets the
// last ~1-2us of latency exposure; if neutral, we are at the roofline.

__device__ __forceinline__ u64 wave_min_u64(u64 k) {
#pragma unroll
    for (int off = 32; off > 0; off >>= 1) {
        u64 o = __shfl_down(k, off, 64);
        if (o < k) k = o;
    }
    return k;
}

__global__ __launch_bounds__(THREADS) void pm_fused(
    const float* __restrict__ pred, const float* __restrict__ gt,
    float* __restrict__ out)
{
    const int tid  = threadIdx.x;
    const int wave = tid >> 6;
    const int lane = tid & 63;
    const int n0   = blockIdx.x * PPB;    // this block's pred rows [n0, n0+PPB)

    // Pred rows are block-uniform -> scalarizable (s_load) by divergence
    // analysis; kept as plain uniform float4 loads.
    float pr0[40], pr1[40];
    {
        const float4* p0 = (const float4*)(pred + (n0 + 0) * 40);
        const float4* p1 = (const float4*)(pred + (n0 + 1) * 40);
#pragma unroll
        for (int q = 0; q < 10; ++q) {
            float4 a = p0[q];
            pr0[4*q+0] = a.x; pr0[4*q+1] = a.y; pr0[4*q+2] = a.z; pr0[4*q+3] = a.w;
            float4 b = p1[q];
            pr1[4*q+0] = b.x; pr1[4*q+1] = b.y; pr1[4*q+2] = b.z; pr1[4*q+3] = b.w;
        }
    }

    // Stream A: m in {tid, 256+tid, 512+tid, 768+tid}   (ascending)
    // Stream B: m in {1024+tid, ..., 1792+tid}          (ascending)
    // Within each stream strict '<' keeps first occurrence; A's indices are
    // all < B's, so u64-min merge keeps (min dist, then min index).
    float a_bd0 = 3.4e38f, a_bd1 = 3.4e38f;
    float b_bd0 = 3.4e38f, b_bd1 = 3.4e38f;
    int   a_bi0 = 0x7fffffff, a_bi1 = 0x7fffffff;
    int   b_bi0 = 0x7fffffff, b_bi1 = 0x7fffffff;

#pragma unroll
    for (int i = 0; i < HALF; ++i) {
        const int mA = i * THREADS + tid;
        const int mB = (i + HALF) * THREADS + tid;
        const float4* gpA = (const float4*)(gt + mA * 40);
        const float4* gpB = (const float4*)(gt + mB * 40);
        float accA0 = 0.0f, accA1 = 0.0f;
        float accB0 = 0.0f, accB1 = 0.0f;
#pragma unroll
        for (int q = 0; q < 10; ++q) {
            float4 gA = gpA[q];
            float4 gB = gpB[q];
            // stream A, pred row 0 — expression-identical to verified form
            {
                float dx0 = pr0[4*q+0] - gA.x;
                float dy0 = pr0[4*q+1] - gA.y;
                float dx1 = pr0[4*q+2] - gA.z;
                float dy1 = pr0[4*q+3] - gA.w;
                accA0 += __builtin_amdgcn_sqrtf(dx0*dx0 + dy0*dy0);
                accA0 += __builtin_amdgcn_sqrtf(dx1*dx1 + dy1*dy1);
            }
            // stream A, pred row 1
            {
                float dx0 = pr1[4*q+0] - gA.x;
                float dy0 = pr1[4*q+1] - gA.y;
                float dx1 = pr1[4*q+2] - gA.z;
                float dy1 = pr1[4*q+3] - gA.w;
                accA1 += __builtin_amdgcn_sqrtf(dx0*dx0 + dy0*dy0);
                accA1 += __builtin_amdgcn_sqrtf(dx1*dx1 + dy1*dy1);
            }
            // stream B, pred row 0
            {
                float dx0 = pr0[4*q+0] - gB.x;
                float dy0 = pr0[4*q+1] - gB.y;
                float dx1 = pr0[4*q+2] - gB.z;
                float dy1 = pr0[4*q+3] - gB.w;
                accB0 += __builtin_amdgcn_sqrtf(dx0*dx0 + dy0*dy0);
                accB0 += __builtin_amdgcn_sqrtf(dx1*dx1 + dy1*dy1);
            }
            // stream B, pred row 1
            {
                float dx0 = pr1[4*q+0] - gB.x;
                float dy0 = pr1[4*q+1] - gB.y;
                float dx1 = pr1[4*q+2] - gB.z;
                float dy1 = pr1[4*q+3] - gB.w;
                accB1 += __builtin_amdgcn_sqrtf(dx0*dx0 + dy0*dy0);
                accB1 += __builtin_amdgcn_sqrtf(dx1*dx1 + dy1*dy1);
            }
        }
        float dA0 = accA0 * (1.0f / P);
        float dA1 = accA1 * (1.0f / P);
        float dB0 = accB0 * (1.0f / P);
        float dB1 = accB1 * (1.0f / P);
        if (dA0 < a_bd0) { a_bd0 = dA0; a_bi0 = mA; }
        if (dA1 < a_bd1) { a_bd1 = dA1; a_bi1 = mA; }
        if (dB0 < b_bd0) { b_bd0 = dB0; b_bi0 = mB; }
        if (dB1 < b_bd1) { b_bd1 = dB1; b_bi1 = mB; }
    }

    // Merge streams via packed keys: u64 min == lexicographic (dist, idx) min.
    u64 kA0 = ((u64)__float_as_uint(a_bd0) << 32) | (unsigned)a_bi0;
    u64 kA1 = ((u64)__float_as_uint(a_bd1) << 32) | (unsigned)a_bi1;
    u64 kB0 = ((u64)__float_as_uint(b_bd0) << 32) | (unsigned)b_bi0;
    u64 kB1 = ((u64)__float_as_uint(b_bd1) << 32) | (unsigned)b_bi1;
    u64 k0 = (kB0 < kA0) ? kB0 : kA0;
    u64 k1 = (kB1 < kA1) ? kB1 : kA1;

    // Wave reduce, then 4-wave LDS reduce. No atomics, no workspace.
    k0 = wave_min_u64(k0);
    k1 = wave_min_u64(k1);

    __shared__ u64 s_k[2][WAVES];
    __shared__ int s_fi[2];
    if (lane == 0) { s_k[0][wave] = k0; s_k[1][wave] = k1; }
    __syncthreads();

    if (tid == 0) {
        u64 b0 = s_k[0][0], b1 = s_k[1][0];
#pragma unroll
        for (int w = 1; w < WAVES; ++w) {
            if (s_k[0][w] < b0) b0 = s_k[0][w];
            if (s_k[1][w] < b1) b1 = s_k[1][w];
        }
        float fd0 = __uint_as_float((unsigned)(b0 >> 32));
        float fd1 = __uint_as_float((unsigned)(b1 >> 32));
        int   fi0 = (int)(unsigned)(b0 & 0xffffffffu);
        int   fi1 = (int)(unsigned)(b1 & 0xffffffffu);
        out[40960 + n0 + 0] = (fd0 > 2.0f) ? 0.0f : expf(-fd0);
        out[40960 + n0 + 1] = (fd1 > 2.0f) ? 0.0f : expf(-fd1);
        out[41984 + n0 + 0] = (float)fi0;
        out[41984 + n0 + 1] = (float)fi1;
        s_fi[0] = fi0;
        s_fi[1] = fi1;
    }
    __syncthreads();

    // Matched-row copy: PPB*40 = 80 floats, threads 0..79, single pass.
    for (int t = tid; t < PPB * 40; t += THREADS) {
        const int r = (t >= 40) ? 1 : 0;
        const int e = t - r * 40;
        out[(n0 + r) * 40 + e] = gt[s_fi[r] * 40 + e];
    }
}

extern "C" void kernel_launch(void* const* d_in, const int* in_sizes, int n_in,
                              void* d_out, int out_size, void* d_ws, size_t ws_size,
                              hipStream_t stream) {
    const float* pred = (const float*)d_in[0];   // (1024, 20, 2) fp32
    const float* gt   = (const float*)d_in[1];   // (2048, 20, 2) fp32
    float* out = (float*)d_out;                  // 43008 floats
    (void)in_sizes; (void)n_in; (void)out_size; (void)d_ws; (void)ws_size;

    pm_fused<<<dim3(BLOCKS), dim3(THREADS), 0, stream>>>(pred, gt, out);
}

// Round 3
// 65.085 us; speedup vs baseline: 1.1302x; 1.1302x over previous
//
#include <hip/hip_runtime.h>

#define N 1024
#define M 2048
#define P 20
#define THREADS 256            // 4 waves/block
#define WAVES 4
#define PPB 2                  // pred rows per block
#define BLOCKS (N / PPB)       // 512 blocks
#define RPT (M / THREADS)      // 8 gt rows per thread

typedef unsigned long long u64;

// out layout (float*): matched_points [0,40960) row n at n*40
//                      confidence     [40960,41984) at 40960+n
//                      indices(float) [41984,43008) at 41984+n
//
// R15 = R13 verbatim revert (verified 65.3us, absmax 0.0).
// R14 post-mortem: dual-stream + full outer unroll doubled live VGPR state
// (80 pred regs + 4 acc streams + 2 float4 batches/iter) -> occupancy/spill
// regression, 65.3 -> 73.6us. Guideline 6: the ~1-2us latency target was not
// worth ~8us of register-pressure cost. DO NOT re-add the unroll.
//
// Structure (R13): single kernel, NO workspace, NO atomics, one dispatch.
// Each block owns PPB=2 pred rows and scans ALL 2048 gt rows (8/thread).
// gt (327 KB) is L2-resident; 512 blocks re-read ~167 MB of L2 (~5us at
// 34.5 TB/s) overlapped with ~5us VALU+sqrt. Zero inter-block communication.
//
// Measured decomposition (R12-R14 rocprof): ~40us harness 256MiB ws-poison
// fill at 83-84% HBM peak + ~18us launch/sync overhead + ~7us this kernel.
// The fill runs regardless of whether we touch d_ws. Kernel is within
// ~1-2us of its overlapped L2/VALU floor.
//
// Numerics: inner-loop expression, accumulation order, acc*(1/P), packed-key
// (dist_bits<<32)|idx first-occurrence argmin, and expf epilogue are
// expression-identical to the absmax-0.0-verified R9-R13 kernels.

__device__ __forceinline__ u64 wave_min_u64(u64 k) {
#pragma unroll
    for (int off = 32; off > 0; off >>= 1) {
        u64 o = __shfl_down(k, off, 64);
        if (o < k) k = o;
    }
    return k;
}

__global__ __launch_bounds__(THREADS) void pm_fused(
    const float* __restrict__ pred, const float* __restrict__ gt,
    float* __restrict__ out)
{
    const int tid  = threadIdx.x;
    const int wave = tid >> 6;
    const int lane = tid & 63;
    const int n0   = blockIdx.x * PPB;    // this block's pred rows [n0, n0+PPB)

    // Pred rows are block-uniform -> compiler can scalarize these loads.
    float pr0[40], pr1[40];
    {
        const float4* p0 = (const float4*)(pred + (n0 + 0) * 40);
        const float4* p1 = (const float4*)(pred + (n0 + 1) * 40);
#pragma unroll
        for (int q = 0; q < 10; ++q) {
            float4 a = p0[q];
            pr0[4*q+0] = a.x; pr0[4*q+1] = a.y; pr0[4*q+2] = a.z; pr0[4*q+3] = a.w;
            float4 b = p1[q];
            pr1[4*q+0] = b.x; pr1[4*q+1] = b.y; pr1[4*q+2] = b.z; pr1[4*q+3] = b.w;
        }
    }

    // Each thread scans gt rows {tid, 256+tid, ...}: ascending m within the
    // thread, so strict '<' keeps the first occurrence; the packed u64 min
    // across threads keeps (min dist, then min index).
    float bd0 = 3.4e38f, bd1 = 3.4e38f;
    int   bi0 = 0x7fffffff, bi1 = 0x7fffffff;
    for (int i = 0; i < RPT; ++i) {
        const int m = i * THREADS + tid;
        const float4* gp = (const float4*)(gt + m * 40);
        float acc0 = 0.0f, acc1 = 0.0f;
#pragma unroll
        for (int q = 0; q < 10; ++q) {
            float4 g = gp[q];
            // pred row 0 — expression-identical to verified form
            float adx0 = pr0[4*q+0] - g.x;
            float ady0 = pr0[4*q+1] - g.y;
            float adx1 = pr0[4*q+2] - g.z;
            float ady1 = pr0[4*q+3] - g.w;
            acc0 += __builtin_amdgcn_sqrtf(adx0*adx0 + ady0*ady0);
            acc0 += __builtin_amdgcn_sqrtf(adx1*adx1 + ady1*ady1);
            // pred row 1
            float bdx0 = pr1[4*q+0] - g.x;
            float bdy0 = pr1[4*q+1] - g.y;
            float bdx1 = pr1[4*q+2] - g.z;
            float bdy1 = pr1[4*q+3] - g.w;
            acc1 += __builtin_amdgcn_sqrtf(bdx0*bdx0 + bdy0*bdy0);
            acc1 += __builtin_amdgcn_sqrtf(bdx1*bdx1 + bdy1*bdy1);
        }
        float d0 = acc0 * (1.0f / P);
        float d1 = acc1 * (1.0f / P);
        if (d0 < bd0) { bd0 = d0; bi0 = m; }
        if (d1 < bd1) { bd1 = d1; bi1 = m; }
    }

    u64 k0 = ((u64)__float_as_uint(bd0) << 32) | (unsigned)bi0;
    u64 k1 = ((u64)__float_as_uint(bd1) << 32) | (unsigned)bi1;

    // Wave reduce, then 4-wave LDS reduce. No atomics, no workspace.
    k0 = wave_min_u64(k0);
    k1 = wave_min_u64(k1);

    __shared__ u64 s_k[2][WAVES];
    __shared__ int s_fi[2];
    if (lane == 0) { s_k[0][wave] = k0; s_k[1][wave] = k1; }
    __syncthreads();

    if (tid == 0) {
        u64 b0 = s_k[0][0], b1 = s_k[1][0];
#pragma unroll
        for (int w = 1; w < WAVES; ++w) {
            if (s_k[0][w] < b0) b0 = s_k[0][w];
            if (s_k[1][w] < b1) b1 = s_k[1][w];
        }
        float fd0 = __uint_as_float((unsigned)(b0 >> 32));
        float fd1 = __uint_as_float((unsigned)(b1 >> 32));
        int   fi0 = (int)(unsigned)(b0 & 0xffffffffu);
        int   fi1 = (int)(unsigned)(b1 & 0xffffffffu);
        out[40960 + n0 + 0] = (fd0 > 2.0f) ? 0.0f : expf(-fd0);
        out[40960 + n0 + 1] = (fd1 > 2.0f) ? 0.0f : expf(-fd1);
        out[41984 + n0 + 0] = (float)fi0;
        out[41984 + n0 + 1] = (float)fi1;
        s_fi[0] = fi0;
        s_fi[1] = fi1;
    }
    __syncthreads();

    // Matched-row copy: PPB*40 = 80 floats, threads 0..79, single pass.
    for (int t = tid; t < PPB * 40; t += THREADS) {
        const int r = (t >= 40) ? 1 : 0;
        const int e = t - r * 40;
        out[(n0 + r) * 40 + e] = gt[s_fi[r] * 40 + e];
    }
}

extern "C" void kernel_launch(void* const* d_in, const int* in_sizes, int n_in,
                              void* d_out, int out_size, void* d_ws, size_t ws_size,
                              hipStream_t stream) {
    const float* pred = (const float*)d_in[0];   // (1024, 20, 2) fp32
    const float* gt   = (const float*)d_in[1];   // (2048, 20, 2) fp32
    float* out = (float*)d_out;                  // 43008 floats
    (void)in_sizes; (void)n_in; (void)out_size; (void)d_ws; (void)ws_size;

    pm_fused<<<dim3(BLOCKS), dim3(THREADS), 0, stream>>>(pred, gt, out);
}